// Round 1
// baseline (241.943 us; speedup 1.0000x reference)
//
#include <hip/hip_runtime.h>

// ContrastiveLoss: B=16, C=256, H=32, Wd=32, K=5, SKIP=1, NEG=16
// Strategy:
//   1) transpose z -> ztr[(y,x,b)][c] (bf16), c -> ct[(y,x,b)][c] (bf16, y<30)
//      Then for slice k, A-row(local p) = ztr row (p + (k+1)*512)  (contiguous!)
//   2) GEMM per k: ztwk[p][o] = sum_c A[p][c] * W[k-1][o][c]  (fp32 accum, bf16 out)
//   3) score kernel: wave per position: pos dot + 16 negative gathered dots,
//      hinge, scaled partial per block
//   4) final reduction kernel -> d_out[0]

typedef unsigned short u16;

#define NEG_  16
#define MAXN_ 15360   // (32-1-1)*32*16
#define TOTROWS 71680 // sum_k (30-kidx)*512, kidx=0..4

__device__ __forceinline__ float bf2f(u16 u) {
    union { unsigned int i; float f; } v; v.i = ((unsigned int)u) << 16; return v.f;
}
__device__ __forceinline__ u16 f2bf(float f) {
    union { unsigned int i; float f; } v; v.f = f;
    unsigned int b = v.i;
    unsigned int r = (b + 0x7FFFu + ((b >> 16) & 1u)) >> 16;
    return (u16)r;
}

// ---------------- transpose ----------------
// grid: (512 = b*32+y, 4 = c-chunk of 64, 2 = {z->ztr, c->ct}), block 256
__global__ __launch_bounds__(256) void transpose_kernel(
    const float* __restrict__ z, const float* __restrict__ cc,
    u16* __restrict__ ztr, u16* __restrict__ ct)
{
    int by = blockIdx.x;
    int b = by >> 5, y = by & 31;
    int c0 = blockIdx.y * 64;
    bool is_c = (blockIdx.z == 1);
    if (is_c && y >= 30) return;
    const float* src = is_c ? cc : z;
    u16* dst = is_c ? ct : ztr;

    __shared__ float tile[64][33];
    int tid = threadIdx.x;
    int x = tid & 31, ci0 = tid >> 5;
#pragma unroll
    for (int i = 0; i < 8; ++i) {
        int ci = ci0 + i * 8;
        tile[ci][x] = src[(((size_t)b * 256 + c0 + ci) * 32 + y) * 32 + x];
    }
    __syncthreads();
    int cw = tid & 63, xw0 = tid >> 6;
#pragma unroll
    for (int i = 0; i < 8; ++i) {
        int xw = xw0 + i * 4;
        dst[(((size_t)y * 32 + xw) * 16 + b) * 256 + c0 + cw] = f2bf(tile[cw][xw]);
    }
}

// ---------------- GEMM ----------------
// out[p][o] = sum_c A[p][c] * Wk[o][c]; A rows bf16 contiguous, Wk fp32 row-major.
// grid: (240 row-tiles(max), 4 col-tiles, 5 k), block 256; tile 64x64, 4x4/thread, KC=16
__global__ __launch_bounds__(256) void gemm_kernel(
    const u16* __restrict__ ztr, const float* __restrict__ Wall,
    u16* __restrict__ ztwk)
{
    int kidx = blockIdx.z;
    int rowTiles = (30 - kidx) * 8;
    if ((int)blockIdx.x >= rowTiles) return;
    int row0 = blockIdx.x * 64;
    int col0 = blockIdx.y * 64;
    int offk = 512 * (30 * kidx - (kidx * (kidx - 1)) / 2);

    const u16* A = ztr + ((size_t)(kidx + 2) * 512 + row0) * 256;
    const float* Wk = Wall + (size_t)kidx * 65536;
    u16* out = ztwk + ((size_t)offk + row0) * 256;

    __shared__ float As[16][64];
    __shared__ float Bs[16][64];

    int tid = threadIdx.x;
    int tx = tid & 15, ty = tid >> 4;
    float acc[4][4] = {{0.f,0.f,0.f,0.f},{0.f,0.f,0.f,0.f},{0.f,0.f,0.f,0.f},{0.f,0.f,0.f,0.f}};

    int lr = tid >> 2;          // 0..63
    int lq = (tid & 3) * 4;     // 0,4,8,12

    for (int c0 = 0; c0 < 256; c0 += 16) {
        ushort4 av = *reinterpret_cast<const ushort4*>(A + (size_t)lr * 256 + c0 + lq);
        As[lq + 0][lr] = bf2f(av.x);
        As[lq + 1][lr] = bf2f(av.y);
        As[lq + 2][lr] = bf2f(av.z);
        As[lq + 3][lr] = bf2f(av.w);
        float4 wv = *reinterpret_cast<const float4*>(Wk + (size_t)(col0 + lr) * 256 + c0 + lq);
        Bs[lq + 0][lr] = wv.x;
        Bs[lq + 1][lr] = wv.y;
        Bs[lq + 2][lr] = wv.z;
        Bs[lq + 3][lr] = wv.w;
        __syncthreads();
#pragma unroll
        for (int kk = 0; kk < 16; ++kk) {
            float a0 = As[kk][ty * 4 + 0], a1 = As[kk][ty * 4 + 1],
                  a2 = As[kk][ty * 4 + 2], a3 = As[kk][ty * 4 + 3];
            float b0 = Bs[kk][tx * 4 + 0], b1 = Bs[kk][tx * 4 + 1],
                  b2 = Bs[kk][tx * 4 + 2], b3 = Bs[kk][tx * 4 + 3];
            acc[0][0] = fmaf(a0, b0, acc[0][0]); acc[0][1] = fmaf(a0, b1, acc[0][1]);
            acc[0][2] = fmaf(a0, b2, acc[0][2]); acc[0][3] = fmaf(a0, b3, acc[0][3]);
            acc[1][0] = fmaf(a1, b0, acc[1][0]); acc[1][1] = fmaf(a1, b1, acc[1][1]);
            acc[1][2] = fmaf(a1, b2, acc[1][2]); acc[1][3] = fmaf(a1, b3, acc[1][3]);
            acc[2][0] = fmaf(a2, b0, acc[2][0]); acc[2][1] = fmaf(a2, b1, acc[2][1]);
            acc[2][2] = fmaf(a2, b2, acc[2][2]); acc[2][3] = fmaf(a2, b3, acc[2][3]);
            acc[3][0] = fmaf(a3, b0, acc[3][0]); acc[3][1] = fmaf(a3, b1, acc[3][1]);
            acc[3][2] = fmaf(a3, b2, acc[3][2]); acc[3][3] = fmaf(a3, b3, acc[3][3]);
        }
        __syncthreads();
    }
#pragma unroll
    for (int i = 0; i < 4; ++i) {
        ushort4 o;
        o.x = f2bf(acc[i][0]); o.y = f2bf(acc[i][1]);
        o.z = f2bf(acc[i][2]); o.w = f2bf(acc[i][3]);
        *reinterpret_cast<ushort4*>(out + (size_t)(ty * 4 + i) * 256 + col0 + tx * 4) = o;
    }
}

// ---------------- scores + hinge ----------------
// wave per position; block = 4 waves; writes one partial per block
__global__ __launch_bounds__(256) void score_kernel(
    const u16* __restrict__ ztwk, const u16* __restrict__ ct,
    const int* __restrict__ rind, float* __restrict__ partials)
{
    __shared__ float red[4];
    int wid = threadIdx.x >> 6, lane = threadIdx.x & 63;
    int gp = blockIdx.x * 4 + wid;

    const int ends0 = 15360, ends1 = 30208, ends2 = 44544, ends3 = 58368;
    int kidx, off;
    if (gp < ends0)      { kidx = 0; off = 0; }
    else if (gp < ends1) { kidx = 1; off = ends0; }
    else if (gp < ends2) { kidx = 2; off = ends1; }
    else if (gp < ends3) { kidx = 3; off = ends2; }
    else                 { kidx = 4; off = ends3; }
    int Nk = (30 - kidx) * 512;
    int local = gp - off;

    // ctx fragment: 4 channels per lane
    ushort4 cv = *reinterpret_cast<const ushort4*>(ct + (size_t)local * 256 + lane * 4);
    float cx0 = bf2f(cv.x), cx1 = bf2f(cv.y), cx2 = bf2f(cv.z), cx3 = bf2f(cv.w);

    // positive
    ushort4 pv = *reinterpret_cast<const ushort4*>(ztwk + (size_t)gp * 256 + lane * 4);
    float p = cx0 * bf2f(pv.x) + cx1 * bf2f(pv.y) + cx2 * bf2f(pv.z) + cx3 * bf2f(pv.w);
#pragma unroll
    for (int s = 1; s < 64; s <<= 1) p += __shfl_xor(p, s);
    float acc = fmaxf(0.f, 1.f - p);

    // negatives: lanes 0..15 (replicated) hold the 16 indices
    int ln = lane & 15;
    int rv = rind[(size_t)kidx * (MAXN_ * NEG_) + (size_t)local * NEG_ + ln];
    int q = (int)((unsigned)rv % (unsigned)Nk);

    float negsum = 0.f;
#pragma unroll
    for (int n = 0; n < 16; ++n) {
        int qn = __shfl(q, n);
        ushort4 nv = *reinterpret_cast<const ushort4*>(ztwk + ((size_t)(off + qn)) * 256 + lane * 4);
        float s = cx0 * bf2f(nv.x) + cx1 * bf2f(nv.y) + cx2 * bf2f(nv.z) + cx3 * bf2f(nv.w);
#pragma unroll
        for (int t = 1; t < 64; t <<= 1) s += __shfl_xor(s, t);
        negsum += fmaxf(0.f, 1.f + s);
    }
    acc += negsum * (1.0f / 16.0f);
    acc *= 1.0f / (float)Nk;

    if (lane == 0) red[wid] = acc;
    __syncthreads();
    if (threadIdx.x == 0)
        partials[blockIdx.x] = red[0] + red[1] + red[2] + red[3];
}

__global__ __launch_bounds__(256) void reduce_kernel(
    const float* __restrict__ partials, float* __restrict__ out, int n)
{
    __shared__ float s[256];
    float a = 0.f;
    for (int i = threadIdx.x; i < n; i += 256) a += partials[i];
    s[threadIdx.x] = a;
    __syncthreads();
    for (int st = 128; st > 0; st >>= 1) {
        if ((int)threadIdx.x < st) s[threadIdx.x] += s[threadIdx.x + st];
        __syncthreads();
    }
    if (threadIdx.x == 0) out[0] = s[0];
}

extern "C" void kernel_launch(void* const* d_in, const int* in_sizes, int n_in,
                              void* d_out, int out_size, void* d_ws, size_t ws_size,
                              hipStream_t stream) {
    const float* z    = (const float*)d_in[0];
    const float* c    = (const float*)d_in[1];
    const float* W    = (const float*)d_in[2];
    const int*   rind = (const int*)d_in[3];

    char* ws = (char*)d_ws;
    u16* ztr      = (u16*)(ws + 0);            // 16384*256*2 = 8,388,608
    u16* ct       = (u16*)(ws + 8388608);      // 15360*256*2 = 7,864,320
    u16* ztwk     = (u16*)(ws + 16252928);     // 71680*256*2 = 36,700,160
    float* parts  = (float*)(ws + 52953088);   // 17920*4
    float* out    = (float*)d_out;

    transpose_kernel<<<dim3(512, 4, 2), 256, 0, stream>>>(z, c, ztr, ct);
    gemm_kernel<<<dim3(240, 4, 5), 256, 0, stream>>>(ztr, W, ztwk);
    score_kernel<<<dim3(TOTROWS / 4), 256, 0, stream>>>(ztwk, ct, rind, parts);
    reduce_kernel<<<dim3(1), 256, 0, stream>>>(parts, out, TOTROWS / 4);
}

// Round 2
// 164.653 us; speedup vs baseline: 1.4694x; 1.4694x over previous
//
#include <hip/hip_runtime.h>

// ContrastiveLoss: B=16, C=256, H=32, Wd=32, K=5, SKIP=1, NEG=16
//   1) transpose z -> ztr[(y,x,b)][c] (bf16), c -> ct[(y,x,b)][c] (bf16, y<30)
//   2) wconv: W fp32 -> bf16
//   3) MFMA GEMM per k: ztwk[p][o] = sum_c ztr[p+ (k+1)*512][c] * Wbf[k][o][c]
//   4) score kernel: wave per position: pos dot + 16 negative gathered dots
//   5) reduction -> d_out[0]

typedef unsigned short u16;
typedef __attribute__((ext_vector_type(8))) short bf16x8;
typedef __attribute__((ext_vector_type(4))) float f32x4;

#define NEG_  16
#define MAXN_ 15360   // (32-1-1)*32*16
#define TOTROWS 71680 // sum_k (30-kidx)*512

__device__ __forceinline__ float bf2f(u16 u) {
    union { unsigned int i; float f; } v; v.i = ((unsigned int)u) << 16; return v.f;
}
__device__ __forceinline__ u16 f2bf(float f) {
    union { unsigned int i; float f; } v; v.f = f;
    unsigned int b = v.i;
    unsigned int r = (b + 0x7FFFu + ((b >> 16) & 1u)) >> 16;
    return (u16)r;
}

// ---------------- transpose ----------------
__global__ __launch_bounds__(256) void transpose_kernel(
    const float* __restrict__ z, const float* __restrict__ cc,
    u16* __restrict__ ztr, u16* __restrict__ ct)
{
    int by = blockIdx.x;
    int b = by >> 5, y = by & 31;
    int c0 = blockIdx.y * 64;
    bool is_c = (blockIdx.z == 1);
    if (is_c && y >= 30) return;
    const float* src = is_c ? cc : z;
    u16* dst = is_c ? ct : ztr;

    __shared__ float tile[64][33];
    int tid = threadIdx.x;
    int x = tid & 31, ci0 = tid >> 5;
#pragma unroll
    for (int i = 0; i < 8; ++i) {
        int ci = ci0 + i * 8;
        tile[ci][x] = src[(((size_t)b * 256 + c0 + ci) * 32 + y) * 32 + x];
    }
    __syncthreads();
    int cw = tid & 63, xw0 = tid >> 6;
#pragma unroll
    for (int i = 0; i < 8; ++i) {
        int xw = xw0 + i * 4;
        dst[(((size_t)y * 32 + xw) * 16 + b) * 256 + c0 + cw] = f2bf(tile[cw][xw]);
    }
}

// ---------------- W fp32 -> bf16 ----------------
// 5*256*256 = 327680 elems, 4 per thread -> 81920 threads -> 320 blocks
__global__ __launch_bounds__(256) void wconv_kernel(
    const float* __restrict__ W, u16* __restrict__ Wbf)
{
    int i = blockIdx.x * 256 + threadIdx.x;
    float4 v = reinterpret_cast<const float4*>(W)[i];
    ushort4 o;
    o.x = f2bf(v.x); o.y = f2bf(v.y); o.z = f2bf(v.z); o.w = f2bf(v.w);
    reinterpret_cast<ushort4*>(Wbf)[i] = o;
}

// ---------------- MFMA GEMM ----------------
// out[p][o] = sum_c A[p][c] * Wk[o][c]; both K-contiguous bf16.
// grid: (240 row-tiles of 64, 5 k), block 256 = 4 waves, wave w -> cols [w*64, w*64+64)
// mfma_f32_16x16x32_bf16; A frag: lane holds row (l&15), k = (l>>4)*8 + 0..7 (16B)
// C/D: col = lane&15, row = (lane>>4)*4 + reg   [m89-verified layout]
__global__ __launch_bounds__(256) void gemm_mfma_kernel(
    const u16* __restrict__ ztr, const u16* __restrict__ Wbf,
    u16* __restrict__ ztwk)
{
    int kidx = blockIdx.y;
    int rowTiles = (30 - kidx) * 8;
    if ((int)blockIdx.x >= rowTiles) return;
    int row0 = blockIdx.x * 64;
    int offk = 512 * (30 * kidx - (kidx * (kidx - 1)) / 2);

    const u16* A  = ztr + ((size_t)(kidx + 2) * 512 + row0) * 256;
    const u16* Bw = Wbf + (size_t)kidx * 65536;
    u16* out = ztwk + ((size_t)offk + row0) * 256;

    int wid = threadIdx.x >> 6, lane = threadIdx.x & 63;
    int col0 = wid * 64;
    int lr = lane & 15, lk = (lane >> 4) * 8;

    const u16* Ab = A  + (size_t)lr * 256 + lk;
    const u16* Bb = Bw + (size_t)(col0 + lr) * 256 + lk;

    f32x4 acc[4][4] = {};

    for (int k0 = 0; k0 < 256; k0 += 32) {
        bf16x8 a[4], b[4];
#pragma unroll
        for (int i = 0; i < 4; ++i)
            a[i] = *reinterpret_cast<const bf16x8*>(Ab + (size_t)i * 16 * 256 + k0);
#pragma unroll
        for (int j = 0; j < 4; ++j)
            b[j] = *reinterpret_cast<const bf16x8*>(Bb + (size_t)j * 16 * 256 + k0);
#pragma unroll
        for (int i = 0; i < 4; ++i)
#pragma unroll
            for (int j = 0; j < 4; ++j)
                acc[i][j] = __builtin_amdgcn_mfma_f32_16x16x32_bf16(a[i], b[j], acc[i][j], 0, 0, 0);
    }

    int rq = (lane >> 4) * 4;
#pragma unroll
    for (int i = 0; i < 4; ++i)
#pragma unroll
        for (int j = 0; j < 4; ++j)
#pragma unroll
            for (int r = 0; r < 4; ++r)
                out[(size_t)(i * 16 + rq + r) * 256 + col0 + j * 16 + lr] =
                    f2bf(acc[i][j][r]);
}

// ---------------- scores + hinge ----------------
__global__ __launch_bounds__(256) void score_kernel(
    const u16* __restrict__ ztwk, const u16* __restrict__ ct,
    const int* __restrict__ rind, float* __restrict__ partials)
{
    __shared__ float red[4];
    int wid = threadIdx.x >> 6, lane = threadIdx.x & 63;
    int gp = blockIdx.x * 4 + wid;

    const int ends0 = 15360, ends1 = 30208, ends2 = 44544, ends3 = 58368;
    int kidx, off;
    if (gp < ends0)      { kidx = 0; off = 0; }
    else if (gp < ends1) { kidx = 1; off = ends0; }
    else if (gp < ends2) { kidx = 2; off = ends1; }
    else if (gp < ends3) { kidx = 3; off = ends2; }
    else                 { kidx = 4; off = ends3; }
    int Nk = (30 - kidx) * 512;
    int local = gp - off;

    ushort4 cv = *reinterpret_cast<const ushort4*>(ct + (size_t)local * 256 + lane * 4);
    float cx0 = bf2f(cv.x), cx1 = bf2f(cv.y), cx2 = bf2f(cv.z), cx3 = bf2f(cv.w);

    ushort4 pv = *reinterpret_cast<const ushort4*>(ztwk + (size_t)gp * 256 + lane * 4);
    float p = cx0 * bf2f(pv.x) + cx1 * bf2f(pv.y) + cx2 * bf2f(pv.z) + cx3 * bf2f(pv.w);
#pragma unroll
    for (int s = 1; s < 64; s <<= 1) p += __shfl_xor(p, s);
    float acc = fmaxf(0.f, 1.f - p);

    int ln = lane & 15;
    int rv = rind[(size_t)kidx * (MAXN_ * NEG_) + (size_t)local * NEG_ + ln];
    int q = (int)((unsigned)rv % (unsigned)Nk);

    float negsum = 0.f;
#pragma unroll
    for (int n = 0; n < 16; ++n) {
        int qn = __shfl(q, n);
        ushort4 nv = *reinterpret_cast<const ushort4*>(ztwk + ((size_t)(off + qn)) * 256 + lane * 4);
        float s = cx0 * bf2f(nv.x) + cx1 * bf2f(nv.y) + cx2 * bf2f(nv.z) + cx3 * bf2f(nv.w);
#pragma unroll
        for (int t = 1; t < 64; t <<= 1) s += __shfl_xor(s, t);
        negsum += fmaxf(0.f, 1.f + s);
    }
    acc += negsum * (1.0f / 16.0f);
    acc *= 1.0f / (float)Nk;

    if (lane == 0) red[wid] = acc;
    __syncthreads();
    if (threadIdx.x == 0)
        partials[blockIdx.x] = red[0] + red[1] + red[2] + red[3];
}

__global__ __launch_bounds__(256) void reduce_kernel(
    const float* __restrict__ partials, float* __restrict__ out, int n)
{
    __shared__ float s[256];
    float a = 0.f;
    for (int i = threadIdx.x; i < n; i += 256) a += partials[i];
    s[threadIdx.x] = a;
    __syncthreads();
    for (int st = 128; st > 0; st >>= 1) {
        if ((int)threadIdx.x < st) s[threadIdx.x] += s[threadIdx.x + st];
        __syncthreads();
    }
    if (threadIdx.x == 0) out[0] = s[0];
}

extern "C" void kernel_launch(void* const* d_in, const int* in_sizes, int n_in,
                              void* d_out, int out_size, void* d_ws, size_t ws_size,
                              hipStream_t stream) {
    const float* z    = (const float*)d_in[0];
    const float* c    = (const float*)d_in[1];
    const float* W    = (const float*)d_in[2];
    const int*   rind = (const int*)d_in[3];

    char* ws = (char*)d_ws;
    u16* ztr      = (u16*)(ws + 0);            // 16384*256*2 = 8,388,608
    u16* ct       = (u16*)(ws + 8388608);      // 15360*256*2 = 7,864,320
    u16* ztwk     = (u16*)(ws + 16252928);     // 71680*256*2 = 36,700,160
    float* parts  = (float*)(ws + 52953088);   // 17920*4 = 71,680
    u16* Wbf      = (u16*)(ws + 53024768);     // 327680*2 = 655,360
    float* out    = (float*)d_out;

    transpose_kernel<<<dim3(512, 4, 2), 256, 0, stream>>>(z, c, ztr, ct);
    wconv_kernel<<<dim3(320), 256, 0, stream>>>(W, Wbf);
    gemm_mfma_kernel<<<dim3(240, 5), 256, 0, stream>>>(ztr, Wbf, ztwk);
    score_kernel<<<dim3(TOTROWS / 4), 256, 0, stream>>>(ztwk, ct, rind, parts);
    reduce_kernel<<<dim3(1), 256, 0, stream>>>(parts, out, TOTROWS / 4);
}

// Round 3
// 163.737 us; speedup vs baseline: 1.4776x; 1.0056x over previous
//
#include <hip/hip_runtime.h>

// ContrastiveLoss: B=16, C=256, H=32, Wd=32, K=5, SKIP=1, NEG=16
//   1) transpose z -> ztr[(y,x,b)][c] (bf16), c -> ct[(y,x,b)][c] (bf16, y<30)
//   2) wconv: W fp32 -> bf16
//   3) MFMA GEMM per k, fp8 output: ztwk8[p][o] = fp8(sum_c ztr[p+(k+1)*512][c] * Wbf[k][o][c])
//      (mfma operands swapped so each lane holds 4 consecutive o of one row -> dword fp8 stores)
//   4) score kernel: wave per position; lane=(neg,quarter); fp8 gathers; 12 shuffles/pos
//   5) reduction -> d_out[0]

typedef unsigned short u16;
typedef unsigned char u8;
typedef unsigned int u32;
typedef __attribute__((ext_vector_type(8))) short bf16x8;
typedef __attribute__((ext_vector_type(4))) float f32x4;
typedef __attribute__((ext_vector_type(2))) float f32x2;

#define NEG_  16
#define MAXN_ 15360   // (32-1-1)*32*16
#define TOTROWS 71680 // sum_k (30-kidx)*512

__device__ __forceinline__ float bf2f(u16 u) {
    union { u32 i; float f; } v; v.i = ((u32)u) << 16; return v.f;
}
__device__ __forceinline__ u16 f2bf(float f) {
    union { u32 i; float f; } v; v.f = f;
    u32 b = v.i;
    return (u16)((b + 0x7FFFu + ((b >> 16) & 1u)) >> 16);
}
__device__ __forceinline__ float lo_bf(u32 u) {
    union { u32 i; float f; } v; v.i = u << 16; return v.f;
}
__device__ __forceinline__ float hi_bf(u32 u) {
    union { u32 i; float f; } v; v.i = u & 0xFFFF0000u; return v.f;
}

// ---------------- transpose ----------------
__global__ __launch_bounds__(256) void transpose_kernel(
    const float* __restrict__ z, const float* __restrict__ cc,
    u16* __restrict__ ztr, u16* __restrict__ ct)
{
    int by = blockIdx.x;
    int b = by >> 5, y = by & 31;
    int c0 = blockIdx.y * 64;
    bool is_c = (blockIdx.z == 1);
    if (is_c && y >= 30) return;
    const float* src = is_c ? cc : z;
    u16* dst = is_c ? ct : ztr;

    __shared__ float tile[64][33];
    int tid = threadIdx.x;
    int x = tid & 31, ci0 = tid >> 5;
#pragma unroll
    for (int i = 0; i < 8; ++i) {
        int ci = ci0 + i * 8;
        tile[ci][x] = src[(((size_t)b * 256 + c0 + ci) * 32 + y) * 32 + x];
    }
    __syncthreads();
    int cw = tid & 63, xw0 = tid >> 6;
#pragma unroll
    for (int i = 0; i < 8; ++i) {
        int xw = xw0 + i * 4;
        dst[(((size_t)y * 32 + xw) * 16 + b) * 256 + c0 + cw] = f2bf(tile[cw][xw]);
    }
}

// ---------------- W fp32 -> bf16 ----------------
__global__ __launch_bounds__(256) void wconv_kernel(
    const float* __restrict__ W, u16* __restrict__ Wbf)
{
    int i = blockIdx.x * 256 + threadIdx.x;
    float4 v = reinterpret_cast<const float4*>(W)[i];
    ushort4 o;
    o.x = f2bf(v.x); o.y = f2bf(v.y); o.z = f2bf(v.z); o.w = f2bf(v.w);
    reinterpret_cast<ushort4*>(Wbf)[i] = o;
}

// ---------------- MFMA GEMM, fp8 out ----------------
// Q = mfma(b[j], a[i]) gives Q[alpha][beta]: alpha=(l>>4)*4+reg = o-within-tile,
// beta = l&15 = ztwk-row-within-tile  => lane holds 4 consecutive o of ONE row.
__global__ __launch_bounds__(256) void gemm_mfma_kernel(
    const u16* __restrict__ ztr, const u16* __restrict__ Wbf,
    u8* __restrict__ ztwk8)
{
    int kidx = blockIdx.y;
    int rowTiles = (30 - kidx) * 8;
    if ((int)blockIdx.x >= rowTiles) return;
    int row0 = blockIdx.x * 64;
    int offk = 512 * (30 * kidx - (kidx * (kidx - 1)) / 2);

    const u16* A  = ztr + ((size_t)(kidx + 2) * 512 + row0) * 256;
    const u16* Bw = Wbf + (size_t)kidx * 65536;
    u8* out = ztwk8 + ((size_t)offk + row0) * 256;

    int wid = threadIdx.x >> 6, lane = threadIdx.x & 63;
    int col0 = wid * 64;
    int lr = lane & 15, lk = (lane >> 4) * 8;

    const u16* Ab = A  + (size_t)lr * 256 + lk;
    const u16* Bb = Bw + (size_t)(col0 + lr) * 256 + lk;

    f32x4 acc[4][4] = {};

    for (int k0 = 0; k0 < 256; k0 += 32) {
        bf16x8 a[4], b[4];
#pragma unroll
        for (int i = 0; i < 4; ++i)
            a[i] = *reinterpret_cast<const bf16x8*>(Ab + (size_t)i * 16 * 256 + k0);
#pragma unroll
        for (int j = 0; j < 4; ++j)
            b[j] = *reinterpret_cast<const bf16x8*>(Bb + (size_t)j * 16 * 256 + k0);
#pragma unroll
        for (int i = 0; i < 4; ++i)
#pragma unroll
            for (int j = 0; j < 4; ++j)
                acc[i][j] = __builtin_amdgcn_mfma_f32_16x16x32_bf16(b[j], a[i], acc[i][j], 0, 0, 0);
    }

    int rq = (lane >> 4) * 4;   // o sub-offset within 16-tile
#pragma unroll
    for (int i = 0; i < 4; ++i) {
#pragma unroll
        for (int j = 0; j < 4; ++j) {
            u32 u = 0;
            u = __builtin_amdgcn_cvt_pk_fp8_f32(acc[i][j][0], acc[i][j][1], u, false);
            u = __builtin_amdgcn_cvt_pk_fp8_f32(acc[i][j][2], acc[i][j][3], u, true);
            *reinterpret_cast<u32*>(out + (size_t)(i * 16 + lr) * 256 + col0 + j * 16 + rq) = u;
        }
    }
}

// ---------------- scores + hinge ----------------
// wave per position. lane l: negative n = l>>2, channel-quarter q = l&3 (64 chans).
__global__ __launch_bounds__(256) void score_kernel(
    const u8* __restrict__ ztwk8, const u16* __restrict__ ct,
    const int* __restrict__ rind, float* __restrict__ partials)
{
    __shared__ float red[4];
    int wid = threadIdx.x >> 6, lane = threadIdx.x & 63;
    int gp = blockIdx.x * 4 + wid;

    const int ends0 = 15360, ends1 = 30208, ends2 = 44544, ends3 = 58368;
    int kidx, off;
    if (gp < ends0)      { kidx = 0; off = 0; }
    else if (gp < ends1) { kidx = 1; off = ends0; }
    else if (gp < ends2) { kidx = 2; off = ends1; }
    else if (gp < ends3) { kidx = 3; off = ends2; }
    else                 { kidx = 4; off = ends3; }
    int Nk = (30 - kidx) * 512;
    int local = gp - off;

    // ---- positive: 4 chans per lane ----
    u32 pw = *reinterpret_cast<const u32*>(ztwk8 + (size_t)gp * 256 + lane * 4);
    ushort4 cv = *reinterpret_cast<const ushort4*>(ct + (size_t)local * 256 + lane * 4);
    f32x2 plo = __builtin_amdgcn_cvt_pk_f32_fp8(pw, false);
    f32x2 phi = __builtin_amdgcn_cvt_pk_f32_fp8(pw, true);
    float p = bf2f(cv.x) * plo.x + bf2f(cv.y) * plo.y
            + bf2f(cv.z) * phi.x + bf2f(cv.w) * phi.y;
#pragma unroll
    for (int s = 1; s < 64; s <<= 1) p += __shfl_xor(p, s);

    // ---- negatives ----
    int n = lane >> 2, q = lane & 3;
    int rv = rind[(size_t)kidx * (MAXN_ * NEG_) + (size_t)local * NEG_ + n];
    int idx = (int)((unsigned)rv % (unsigned)Nk);

    const uint4* nrow = reinterpret_cast<const uint4*>(ztwk8 + ((size_t)(off + idx)) * 256 + q * 64);
    const uint4* crow = reinterpret_cast<const uint4*>(ct + (size_t)local * 256 + q * 64);

    float d = 0.f;
#pragma unroll
    for (int t = 0; t < 4; ++t) {        // 16 chans per iter
        uint4 nb = nrow[t];
        uint4 ca = crow[2 * t];
        uint4 cb = crow[2 * t + 1];
        f32x2 f;
        f = __builtin_amdgcn_cvt_pk_f32_fp8(nb.x, false);
        d = fmaf(lo_bf(ca.x), f.x, d); d = fmaf(hi_bf(ca.x), f.y, d);
        f = __builtin_amdgcn_cvt_pk_f32_fp8(nb.x, true);
        d = fmaf(lo_bf(ca.y), f.x, d); d = fmaf(hi_bf(ca.y), f.y, d);
        f = __builtin_amdgcn_cvt_pk_f32_fp8(nb.y, false);
        d = fmaf(lo_bf(ca.z), f.x, d); d = fmaf(hi_bf(ca.z), f.y, d);
        f = __builtin_amdgcn_cvt_pk_f32_fp8(nb.y, true);
        d = fmaf(lo_bf(ca.w), f.x, d); d = fmaf(hi_bf(ca.w), f.y, d);
        f = __builtin_amdgcn_cvt_pk_f32_fp8(nb.z, false);
        d = fmaf(lo_bf(cb.x), f.x, d); d = fmaf(hi_bf(cb.x), f.y, d);
        f = __builtin_amdgcn_cvt_pk_f32_fp8(nb.z, true);
        d = fmaf(lo_bf(cb.y), f.x, d); d = fmaf(hi_bf(cb.y), f.y, d);
        f = __builtin_amdgcn_cvt_pk_f32_fp8(nb.w, false);
        d = fmaf(lo_bf(cb.z), f.x, d); d = fmaf(hi_bf(cb.z), f.y, d);
        f = __builtin_amdgcn_cvt_pk_f32_fp8(nb.w, true);
        d = fmaf(lo_bf(cb.w), f.x, d); d = fmaf(hi_bf(cb.w), f.y, d);
    }
    // intra-group (4 lanes) reduce -> full dot on every lane of group
    d += __shfl_xor(d, 1);
    d += __shfl_xor(d, 2);
    float h = fmaxf(0.f, 1.f + d);
    // across the 16 groups (one lane-offset per group kept fixed)
    h += __shfl_xor(h, 4);
    h += __shfl_xor(h, 8);
    h += __shfl_xor(h, 16);
    h += __shfl_xor(h, 32);

    float acc = fmaxf(0.f, 1.f - p) + h * (1.0f / 16.0f);
    acc *= 1.0f / (float)Nk;

    if (lane == 0) red[wid] = acc;
    __syncthreads();
    if (threadIdx.x == 0)
        partials[blockIdx.x] = red[0] + red[1] + red[2] + red[3];
}

__global__ __launch_bounds__(256) void reduce_kernel(
    const float* __restrict__ partials, float* __restrict__ out, int n)
{
    __shared__ float s[256];
    float a = 0.f;
    for (int i = threadIdx.x; i < n; i += 256) a += partials[i];
    s[threadIdx.x] = a;
    __syncthreads();
    for (int st = 128; st > 0; st >>= 1) {
        if ((int)threadIdx.x < st) s[threadIdx.x] += s[threadIdx.x + st];
        __syncthreads();
    }
    if (threadIdx.x == 0) out[0] = s[0];
}

extern "C" void kernel_launch(void* const* d_in, const int* in_sizes, int n_in,
                              void* d_out, int out_size, void* d_ws, size_t ws_size,
                              hipStream_t stream) {
    const float* z    = (const float*)d_in[0];
    const float* c    = (const float*)d_in[1];
    const float* W    = (const float*)d_in[2];
    const int*   rind = (const int*)d_in[3];

    char* ws = (char*)d_ws;
    u16* ztr      = (u16*)(ws + 0);            // 16384*256*2 = 8,388,608
    u16* ct       = (u16*)(ws + 8388608);      // 15360*256*2 = 7,864,320
    u8*  ztwk8    = (u8*) (ws + 16252928);     // 71680*256   = 18,350,080
    float* parts  = (float*)(ws + 34603008);   // 17920*4
    u16* Wbf      = (u16*)(ws + 34674688);     // 327680*2 = 655,360
    float* out    = (float*)d_out;

    transpose_kernel<<<dim3(512, 4, 2), 256, 0, stream>>>(z, c, ztr, ct);
    wconv_kernel<<<dim3(320), 256, 0, stream>>>(W, Wbf);
    gemm_mfma_kernel<<<dim3(240, 5), 256, 0, stream>>>(ztr, Wbf, ztwk8);
    score_kernel<<<dim3(TOTROWS / 4), 256, 0, stream>>>(ztwk8, ct, rind, parts);
    reduce_kernel<<<dim3(1), 256, 0, stream>>>(parts, out, TOTROWS / 4);
}

// Round 4
// 111.541 us; speedup vs baseline: 2.1691x; 1.4679x over previous
//
#include <hip/hip_runtime.h>

// ContrastiveLoss: B=16, C=256, H=32, Wd=32, K=5, SKIP=1, NEG=16
//   1) transpose z -> ztr[(y,x,b)][c] (bf16); c -> ctf[(y,x,b)][c] (fp32, y<30);
//      + fused W fp32->bf16 (grid z=2)
//   2) MFMA GEMM per k, fp8 output (swapped operands -> lane holds 4 consecutive o of one row)
//   3) score kernel: wave per position; lane=(neg-slot r, chunk c16); each 16-lane
//      group reads one 256B negative row contiguously; fp32 ctx; cond-sub modulo
//   4) reduction -> d_out[0]

typedef unsigned short u16;
typedef unsigned char u8;
typedef unsigned int u32;
typedef __attribute__((ext_vector_type(8))) short bf16x8;
typedef __attribute__((ext_vector_type(4))) float f32x4;
typedef __attribute__((ext_vector_type(2))) float f32x2;

#define NEG_  16
#define MAXN_ 15360   // (32-1-1)*32*16
#define TOTROWS 71680 // sum_k (30-kidx)*512

__device__ __forceinline__ u16 f2bf(float f) {
    union { u32 i; float f; } v; v.f = f;
    u32 b = v.i;
    return (u16)((b + 0x7FFFu + ((b >> 16) & 1u)) >> 16);
}

// ---------------- transpose + wconv ----------------
// z==0: z -> ztr (bf16); z==1: c -> ctf (fp32, y<30); z==2: W -> Wbf (320 blocks)
__global__ __launch_bounds__(256) void transpose_kernel(
    const float* __restrict__ z, const float* __restrict__ cc,
    const float* __restrict__ W,
    u16* __restrict__ ztr, float* __restrict__ ctf, u16* __restrict__ Wbf)
{
    int tid = threadIdx.x;
    if (blockIdx.z == 2) {
        if (blockIdx.y != 0 || blockIdx.x >= 320) return;
        int i = blockIdx.x * 256 + tid;
        float4 v = reinterpret_cast<const float4*>(W)[i];
        ushort4 o;
        o.x = f2bf(v.x); o.y = f2bf(v.y); o.z = f2bf(v.z); o.w = f2bf(v.w);
        reinterpret_cast<ushort4*>(Wbf)[i] = o;
        return;
    }
    int by = blockIdx.x;
    int b = by >> 5, y = by & 31;
    int c0 = blockIdx.y * 64;
    bool is_c = (blockIdx.z == 1);
    if (is_c && y >= 30) return;
    const float* src = is_c ? cc : z;

    __shared__ float tile[64][33];
    int x = tid & 31, ci0 = tid >> 5;
#pragma unroll
    for (int i = 0; i < 8; ++i) {
        int ci = ci0 + i * 8;
        tile[ci][x] = src[(((size_t)b * 256 + c0 + ci) * 32 + y) * 32 + x];
    }
    __syncthreads();
    int cw = tid & 63, xw0 = tid >> 6;
    if (is_c) {
#pragma unroll
        for (int i = 0; i < 8; ++i) {
            int xw = xw0 + i * 4;
            ctf[(((size_t)y * 32 + xw) * 16 + b) * 256 + c0 + cw] = tile[cw][xw];
        }
    } else {
#pragma unroll
        for (int i = 0; i < 8; ++i) {
            int xw = xw0 + i * 4;
            ztr[(((size_t)y * 32 + xw) * 16 + b) * 256 + c0 + cw] = f2bf(tile[cw][xw]);
        }
    }
}

// ---------------- MFMA GEMM, fp8 out ----------------
__global__ __launch_bounds__(256) void gemm_mfma_kernel(
    const u16* __restrict__ ztr, const u16* __restrict__ Wbf,
    u8* __restrict__ ztwk8)
{
    int kidx = blockIdx.y;
    int rowTiles = (30 - kidx) * 8;
    if ((int)blockIdx.x >= rowTiles) return;
    int row0 = blockIdx.x * 64;
    int offk = 512 * (30 * kidx - (kidx * (kidx - 1)) / 2);

    const u16* A  = ztr + ((size_t)(kidx + 2) * 512 + row0) * 256;
    const u16* Bw = Wbf + (size_t)kidx * 65536;
    u8* out = ztwk8 + ((size_t)offk + row0) * 256;

    int wid = threadIdx.x >> 6, lane = threadIdx.x & 63;
    int col0 = wid * 64;
    int lr = lane & 15, lk = (lane >> 4) * 8;

    const u16* Ab = A  + (size_t)lr * 256 + lk;
    const u16* Bb = Bw + (size_t)(col0 + lr) * 256 + lk;

    f32x4 acc[4][4] = {};

    for (int k0 = 0; k0 < 256; k0 += 32) {
        bf16x8 a[4], b[4];
#pragma unroll
        for (int i = 0; i < 4; ++i)
            a[i] = *reinterpret_cast<const bf16x8*>(Ab + (size_t)i * 16 * 256 + k0);
#pragma unroll
        for (int j = 0; j < 4; ++j)
            b[j] = *reinterpret_cast<const bf16x8*>(Bb + (size_t)j * 16 * 256 + k0);
#pragma unroll
        for (int i = 0; i < 4; ++i)
#pragma unroll
            for (int j = 0; j < 4; ++j)
                acc[i][j] = __builtin_amdgcn_mfma_f32_16x16x32_bf16(b[j], a[i], acc[i][j], 0, 0, 0);
    }

    int rq = (lane >> 4) * 4;
#pragma unroll
    for (int i = 0; i < 4; ++i) {
#pragma unroll
        for (int j = 0; j < 4; ++j) {
            u32 u = 0;
            u = __builtin_amdgcn_cvt_pk_fp8_f32(acc[i][j][0], acc[i][j][1], u, false);
            u = __builtin_amdgcn_cvt_pk_fp8_f32(acc[i][j][2], acc[i][j][3], u, true);
            *reinterpret_cast<u32*>(out + (size_t)(i * 16 + lr) * 256 + col0 + j * 16 + rq) = u;
        }
    }
}

// ---------------- scores + hinge ----------------
__device__ __forceinline__ float dot16(uint4 nb, float4 c0, float4 c1, float4 c2, float4 c3) {
    f32x2 f;
    float d0 = 0.f, d1 = 0.f;
    f = __builtin_amdgcn_cvt_pk_f32_fp8(nb.x, false);
    d0 = fmaf(c0.x, f.x, d0); d0 = fmaf(c0.y, f.y, d0);
    f = __builtin_amdgcn_cvt_pk_f32_fp8(nb.x, true);
    d0 = fmaf(c0.z, f.x, d0); d0 = fmaf(c0.w, f.y, d0);
    f = __builtin_amdgcn_cvt_pk_f32_fp8(nb.y, false);
    d0 = fmaf(c1.x, f.x, d0); d0 = fmaf(c1.y, f.y, d0);
    f = __builtin_amdgcn_cvt_pk_f32_fp8(nb.y, true);
    d0 = fmaf(c1.z, f.x, d0); d0 = fmaf(c1.w, f.y, d0);
    f = __builtin_amdgcn_cvt_pk_f32_fp8(nb.z, false);
    d1 = fmaf(c2.x, f.x, d1); d1 = fmaf(c2.y, f.y, d1);
    f = __builtin_amdgcn_cvt_pk_f32_fp8(nb.z, true);
    d1 = fmaf(c2.z, f.x, d1); d1 = fmaf(c2.w, f.y, d1);
    f = __builtin_amdgcn_cvt_pk_f32_fp8(nb.w, false);
    d1 = fmaf(c3.x, f.x, d1); d1 = fmaf(c3.y, f.y, d1);
    f = __builtin_amdgcn_cvt_pk_f32_fp8(nb.w, true);
    d1 = fmaf(c3.z, f.x, d1); d1 = fmaf(c3.w, f.y, d1);
    return d0 + d1;
}

// wave per position; lane = (r = neg-slot 0..3, c16 = 16B chunk 0..15).
// Pass j: negative n = j*4 + r; 16 lanes of group r read row n contiguously.
__global__ __launch_bounds__(256) void score_kernel(
    const u8* __restrict__ ztwk8, const float* __restrict__ ctf,
    const int* __restrict__ rind, float* __restrict__ partials)
{
    __shared__ float red[4];
    int wid = threadIdx.x >> 6, lane = threadIdx.x & 63;
    int gp = blockIdx.x * 4 + wid;

    const int ends0 = 15360, ends1 = 30208, ends2 = 44544, ends3 = 58368;
    int kidx, off;
    if (gp < ends0)      { kidx = 0; off = 0; }
    else if (gp < ends1) { kidx = 1; off = ends0; }
    else if (gp < ends2) { kidx = 2; off = ends1; }
    else if (gp < ends3) { kidx = 3; off = ends2; }
    else                 { kidx = 4; off = ends3; }
    int Nk = (30 - kidx) * 512;
    int local = gp - off;

    int r = lane >> 4, c16 = lane & 15;

    // indices first (to get row loads in flight early)
    const int* rbase = rind + (size_t)kidx * (MAXN_ * NEG_) + (size_t)local * NEG_ + r;
    int rv0 = rbase[0], rv1 = rbase[4], rv2 = rbase[8], rv3 = rbase[12];
    int i0 = rv0 >= Nk ? rv0 - Nk : rv0;
    int i1 = rv1 >= Nk ? rv1 - Nk : rv1;
    int i2 = rv2 >= Nk ? rv2 - Nk : rv2;
    int i3 = rv3 >= Nk ? rv3 - Nk : rv3;

    const u8* zb = ztwk8 + (size_t)off * 256 + c16 * 16;
    uint4 nb0 = *reinterpret_cast<const uint4*>(zb + (size_t)i0 * 256);
    uint4 nb1 = *reinterpret_cast<const uint4*>(zb + (size_t)i1 * 256);
    uint4 nb2 = *reinterpret_cast<const uint4*>(zb + (size_t)i2 * 256);
    uint4 nb3 = *reinterpret_cast<const uint4*>(zb + (size_t)i3 * 256);
    uint4 pb  = *reinterpret_cast<const uint4*>(ztwk8 + (size_t)gp * 256 + c16 * 16);

    const float4* cb = reinterpret_cast<const float4*>(ctf + (size_t)local * 256 + c16 * 16);
    float4 c0 = cb[0], c1 = cb[1], c2 = cb[2], c3 = cb[3];

    // positive (computed redundantly in all 4 groups; only group 0 contributes)
    float p = dot16(pb, c0, c1, c2, c3);
    p += __shfl_xor(p, 1); p += __shfl_xor(p, 2);
    p += __shfl_xor(p, 4); p += __shfl_xor(p, 8);
    float val = (r == 0) ? fmaxf(0.f, 1.f - p) : 0.f;

    // negatives
    float d;
    float h = 0.f;
    d = dot16(nb0, c0, c1, c2, c3);
    d += __shfl_xor(d, 1); d += __shfl_xor(d, 2);
    d += __shfl_xor(d, 4); d += __shfl_xor(d, 8);
    h += fmaxf(0.f, 1.f + d);
    d = dot16(nb1, c0, c1, c2, c3);
    d += __shfl_xor(d, 1); d += __shfl_xor(d, 2);
    d += __shfl_xor(d, 4); d += __shfl_xor(d, 8);
    h += fmaxf(0.f, 1.f + d);
    d = dot16(nb2, c0, c1, c2, c3);
    d += __shfl_xor(d, 1); d += __shfl_xor(d, 2);
    d += __shfl_xor(d, 4); d += __shfl_xor(d, 8);
    h += fmaxf(0.f, 1.f + d);
    d = dot16(nb3, c0, c1, c2, c3);
    d += __shfl_xor(d, 1); d += __shfl_xor(d, 2);
    d += __shfl_xor(d, 4); d += __shfl_xor(d, 8);
    h += fmaxf(0.f, 1.f + d);

    val += h * (1.0f / 16.0f);
    // sum the 4 groups (each holds its own negatives' hinge sum; group 0 adds positive)
    val += __shfl_xor(val, 16);
    val += __shfl_xor(val, 32);
    val *= 1.0f / (float)Nk;

    if (lane == 0) red[wid] = val;
    __syncthreads();
    if (threadIdx.x == 0)
        partials[blockIdx.x] = red[0] + red[1] + red[2] + red[3];
}

__global__ __launch_bounds__(256) void reduce_kernel(
    const float* __restrict__ partials, float* __restrict__ out, int n)
{
    __shared__ float s[256];
    float a = 0.f;
    for (int i = threadIdx.x; i < n; i += 256) a += partials[i];
    s[threadIdx.x] = a;
    __syncthreads();
    for (int st = 128; st > 0; st >>= 1) {
        if ((int)threadIdx.x < st) s[threadIdx.x] += s[threadIdx.x + st];
        __syncthreads();
    }
    if (threadIdx.x == 0) out[0] = s[0];
}

extern "C" void kernel_launch(void* const* d_in, const int* in_sizes, int n_in,
                              void* d_out, int out_size, void* d_ws, size_t ws_size,
                              hipStream_t stream) {
    const float* z    = (const float*)d_in[0];
    const float* c    = (const float*)d_in[1];
    const float* W    = (const float*)d_in[2];
    const int*   rind = (const int*)d_in[3];

    char* ws = (char*)d_ws;
    u16*   ztr   = (u16*)  (ws + 0);            // 16384*256*2 = 8,388,608
    float* ctf   = (float*)(ws + 8388608);      // 15360*256*4 = 15,728,640
    u8*    ztwk8 = (u8*)   (ws + 24117248);     // 71680*256   = 18,350,080
    float* parts = (float*)(ws + 42467328);     // 17920*4     = 71,680
    u16*   Wbf   = (u16*)  (ws + 42539008);     // 327680*2    = 655,360
    float* out   = (float*)d_out;

    transpose_kernel<<<dim3(512, 4, 3), 256, 0, stream>>>(z, c, W, ztr, ctf, Wbf);
    gemm_mfma_kernel<<<dim3(240, 5), 256, 0, stream>>>(ztr, Wbf, ztwk8);
    score_kernel<<<dim3(TOTROWS / 4), 256, 0, stream>>>(ztwk8, ctf, rind, parts);
    reduce_kernel<<<dim3(1), 256, 0, stream>>>(parts, out, TOTROWS / 4);
}

// Round 5
// 90.007 us; speedup vs baseline: 2.6881x; 1.2393x over previous
//
#include <hip/hip_runtime.h>

// ContrastiveLoss: B=16, C=256, H=32, Wd=32, K=5, SKIP=1, NEG=16
//   1) transpose z -> ztr (bf16, MFMA-fragment-major); c -> ctf (fp32, y<30);
//      fused W fp32->bf16 fragment-major (grid z=2)
//   2) MFMA GEMM per k, fp8 output; A/B fragment loads are contiguous 16B/lane
//   3) score kernel: wave per position; 16-lane groups read negative rows contiguously
//   4) reduction -> d_out[0]
//
// Fragment-major layout for a [rows][256] bf16 matrix:
//   addr(row,k) = ((row>>4)*8 + (k>>5))*512 + ((row&15) + 16*((k>>3)&3))*8 + (k&7)
// so a wave's mfma_16x16x32 A/B fragment load at (tile,kblk) is lane*8 contiguous.

typedef unsigned short u16;
typedef unsigned char u8;
typedef unsigned int u32;
typedef __attribute__((ext_vector_type(8))) short bf16x8;
typedef __attribute__((ext_vector_type(4))) float f32x4;
typedef __attribute__((ext_vector_type(2))) float f32x2;

#define NEG_  16
#define MAXN_ 15360   // (32-1-1)*32*16
#define TOTROWS 71680 // sum_k (30-kidx)*512

__device__ __forceinline__ u16 f2bf(float f) {
    union { u32 i; float f; } v; v.f = f;
    u32 b = v.i;
    return (u16)((b + 0x7FFFu + ((b >> 16) & 1u)) >> 16);
}

__device__ __forceinline__ size_t frag_addr(int row, int k) {
    return ((size_t)(row >> 4) * 8 + (k >> 5)) * 512
         + (size_t)((row & 15) + 16 * ((k >> 3) & 3)) * 8 + (k & 7);
}

// ---------------- transpose + wconv ----------------
// z==0: z -> ztr (bf16 frag-major); z==1: c -> ctf (fp32 linear, y<30); z==2: W -> Wbf (frag-major)
__global__ __launch_bounds__(256) void transpose_kernel(
    const float* __restrict__ z, const float* __restrict__ cc,
    const float* __restrict__ W,
    u16* __restrict__ ztr, float* __restrict__ ctf, u16* __restrict__ Wbf)
{
    int tid = threadIdx.x;
    if (blockIdx.z == 2) {
        if (blockIdx.y != 0 || blockIdx.x >= 320) return;
        int i4 = blockIdx.x * 256 + tid;
        float4 v = reinterpret_cast<const float4*>(W)[i4];
        int e = i4 * 4;
        int kw = e >> 16;
        int rem = e & 65535;
        int o = rem >> 8, c = rem & 255;
        size_t base = (size_t)kw * 65536 + frag_addr(o, c);
        ushort4 u;
        u.x = f2bf(v.x); u.y = f2bf(v.y); u.z = f2bf(v.z); u.w = f2bf(v.w);
        *reinterpret_cast<ushort4*>(Wbf + base) = u;
        return;
    }
    int by = blockIdx.x;
    int b = by >> 5, y = by & 31;
    int c0 = blockIdx.y * 64;
    bool is_c = (blockIdx.z == 1);
    if (is_c && y >= 30) return;
    const float* src = is_c ? cc : z;

    __shared__ float ts[64][33];
    int x = tid & 31, ci0 = tid >> 5;
#pragma unroll
    for (int i = 0; i < 8; ++i) {
        int ci = ci0 + i * 8;
        ts[ci][x] = src[(((size_t)b * 256 + c0 + ci) * 32 + y) * 32 + x];
    }
    __syncthreads();
    int cw = tid & 63, xw0 = tid >> 6;
    if (is_c) {
#pragma unroll
        for (int i = 0; i < 8; ++i) {
            int xw = xw0 + i * 4;
            ctf[(((size_t)y * 32 + xw) * 16 + b) * 256 + c0 + cw] = ts[cw][xw];
        }
    } else {
        int k = c0 + cw;
#pragma unroll
        for (int i = 0; i < 8; ++i) {
            int xw = xw0 + i * 4;
            int row = (y * 32 + xw) * 16 + b;
            ztr[frag_addr(row, k)] = f2bf(ts[cw][xw]);
        }
    }
}

// ---------------- MFMA GEMM, fp8 out ----------------
// Fragment loads fully coalesced from frag-major ztr / Wbf.
__global__ __launch_bounds__(256) void gemm_mfma_kernel(
    const u16* __restrict__ ztr, const u16* __restrict__ Wbf,
    u8* __restrict__ ztwk8)
{
    int kidx = blockIdx.y;
    int rowTiles = (30 - kidx) * 8;
    if ((int)blockIdx.x >= rowTiles) return;
    int row0 = blockIdx.x * 64;
    int offk = 512 * (30 * kidx - (kidx * (kidx - 1)) / 2);

    int tile0 = (((kidx + 2) * 512 + row0) >> 4);      // A tile index
    const u16* Bsw = Wbf + (size_t)kidx * 65536;
    u8* out = ztwk8 + ((size_t)offk + row0) * 256;

    int wid = threadIdx.x >> 6, lane = threadIdx.x & 63;
    int col0 = wid * 64;

    f32x4 acc[4][4] = {};

    for (int kb = 0; kb < 8; ++kb) {
        bf16x8 a[4], b[4];
#pragma unroll
        for (int i = 0; i < 4; ++i)
            a[i] = *reinterpret_cast<const bf16x8*>(
                ztr + ((size_t)(tile0 + i) * 8 + kb) * 512 + lane * 8);
#pragma unroll
        for (int j = 0; j < 4; ++j)
            b[j] = *reinterpret_cast<const bf16x8*>(
                Bsw + ((size_t)(wid * 4 + j) * 8 + kb) * 512 + lane * 8);
#pragma unroll
        for (int i = 0; i < 4; ++i)
#pragma unroll
            for (int j = 0; j < 4; ++j)
                acc[i][j] = __builtin_amdgcn_mfma_f32_16x16x32_bf16(b[j], a[i], acc[i][j], 0, 0, 0);
    }

    int lr = lane & 15;
    int rq = (lane >> 4) * 4;
#pragma unroll
    for (int i = 0; i < 4; ++i) {
#pragma unroll
        for (int j = 0; j < 4; ++j) {
            u32 u = 0;
            u = __builtin_amdgcn_cvt_pk_fp8_f32(acc[i][j][0], acc[i][j][1], u, false);
            u = __builtin_amdgcn_cvt_pk_fp8_f32(acc[i][j][2], acc[i][j][3], u, true);
            *reinterpret_cast<u32*>(out + (size_t)(i * 16 + lr) * 256 + col0 + j * 16 + rq) = u;
        }
    }
}

// ---------------- scores + hinge ----------------
__device__ __forceinline__ float dot16(uint4 nb, float4 c0, float4 c1, float4 c2, float4 c3) {
    f32x2 f;
    float d0 = 0.f, d1 = 0.f;
    f = __builtin_amdgcn_cvt_pk_f32_fp8(nb.x, false);
    d0 = fmaf(c0.x, f.x, d0); d0 = fmaf(c0.y, f.y, d0);
    f = __builtin_amdgcn_cvt_pk_f32_fp8(nb.x, true);
    d0 = fmaf(c0.z, f.x, d0); d0 = fmaf(c0.w, f.y, d0);
    f = __builtin_amdgcn_cvt_pk_f32_fp8(nb.y, false);
    d0 = fmaf(c1.x, f.x, d0); d0 = fmaf(c1.y, f.y, d0);
    f = __builtin_amdgcn_cvt_pk_f32_fp8(nb.y, true);
    d0 = fmaf(c1.z, f.x, d0); d0 = fmaf(c1.w, f.y, d0);
    f = __builtin_amdgcn_cvt_pk_f32_fp8(nb.z, false);
    d1 = fmaf(c2.x, f.x, d1); d1 = fmaf(c2.y, f.y, d1);
    f = __builtin_amdgcn_cvt_pk_f32_fp8(nb.z, true);
    d1 = fmaf(c2.z, f.x, d1); d1 = fmaf(c2.w, f.y, d1);
    f = __builtin_amdgcn_cvt_pk_f32_fp8(nb.w, false);
    d1 = fmaf(c3.x, f.x, d1); d1 = fmaf(c3.y, f.y, d1);
    f = __builtin_amdgcn_cvt_pk_f32_fp8(nb.w, true);
    d1 = fmaf(c3.z, f.x, d1); d1 = fmaf(c3.w, f.y, d1);
    return d0 + d1;
}

__global__ __launch_bounds__(256) void score_kernel(
    const u8* __restrict__ ztwk8, const float* __restrict__ ctf,
    const int* __restrict__ rind, float* __restrict__ partials)
{
    __shared__ float red[4];
    int wid = threadIdx.x >> 6, lane = threadIdx.x & 63;
    int gp = blockIdx.x * 4 + wid;

    const int ends0 = 15360, ends1 = 30208, ends2 = 44544, ends3 = 58368;
    int kidx, off;
    if (gp < ends0)      { kidx = 0; off = 0; }
    else if (gp < ends1) { kidx = 1; off = ends0; }
    else if (gp < ends2) { kidx = 2; off = ends1; }
    else if (gp < ends3) { kidx = 3; off = ends2; }
    else                 { kidx = 4; off = ends3; }
    int Nk = (30 - kidx) * 512;
    int local = gp - off;

    int r = lane >> 4, c16 = lane & 15;

    const int* rbase = rind + (size_t)kidx * (MAXN_ * NEG_) + (size_t)local * NEG_ + r;
    int rv0 = rbase[0], rv1 = rbase[4], rv2 = rbase[8], rv3 = rbase[12];
    int i0 = rv0 >= Nk ? rv0 - Nk : rv0;
    int i1 = rv1 >= Nk ? rv1 - Nk : rv1;
    int i2 = rv2 >= Nk ? rv2 - Nk : rv2;
    int i3 = rv3 >= Nk ? rv3 - Nk : rv3;

    const u8* zb = ztwk8 + (size_t)off * 256 + c16 * 16;
    uint4 nb0 = *reinterpret_cast<const uint4*>(zb + (size_t)i0 * 256);
    uint4 nb1 = *reinterpret_cast<const uint4*>(zb + (size_t)i1 * 256);
    uint4 nb2 = *reinterpret_cast<const uint4*>(zb + (size_t)i2 * 256);
    uint4 nb3 = *reinterpret_cast<const uint4*>(zb + (size_t)i3 * 256);
    uint4 pb  = *reinterpret_cast<const uint4*>(ztwk8 + (size_t)gp * 256 + c16 * 16);

    const float4* cb = reinterpret_cast<const float4*>(ctf + (size_t)local * 256 + c16 * 16);
    float4 c0 = cb[0], c1 = cb[1], c2 = cb[2], c3 = cb[3];

    float p = dot16(pb, c0, c1, c2, c3);
    p += __shfl_xor(p, 1); p += __shfl_xor(p, 2);
    p += __shfl_xor(p, 4); p += __shfl_xor(p, 8);
    float val = (r == 0) ? fmaxf(0.f, 1.f - p) : 0.f;

    float d;
    float h = 0.f;
    d = dot16(nb0, c0, c1, c2, c3);
    d += __shfl_xor(d, 1); d += __shfl_xor(d, 2);
    d += __shfl_xor(d, 4); d += __shfl_xor(d, 8);
    h += fmaxf(0.f, 1.f + d);
    d = dot16(nb1, c0, c1, c2, c3);
    d += __shfl_xor(d, 1); d += __shfl_xor(d, 2);
    d += __shfl_xor(d, 4); d += __shfl_xor(d, 8);
    h += fmaxf(0.f, 1.f + d);
    d = dot16(nb2, c0, c1, c2, c3);
    d += __shfl_xor(d, 1); d += __shfl_xor(d, 2);
    d += __shfl_xor(d, 4); d += __shfl_xor(d, 8);
    h += fmaxf(0.f, 1.f + d);
    d = dot16(nb3, c0, c1, c2, c3);
    d += __shfl_xor(d, 1); d += __shfl_xor(d, 2);
    d += __shfl_xor(d, 4); d += __shfl_xor(d, 8);
    h += fmaxf(0.f, 1.f + d);

    val += h * (1.0f / 16.0f);
    val += __shfl_xor(val, 16);
    val += __shfl_xor(val, 32);
    val *= 1.0f / (float)Nk;

    if (lane == 0) red[wid] = val;
    __syncthreads();
    if (threadIdx.x == 0)
        partials[blockIdx.x] = red[0] + red[1] + red[2] + red[3];
}

__global__ __launch_bounds__(256) void reduce_kernel(
    const float* __restrict__ partials, float* __restrict__ out, int n)
{
    __shared__ float s[256];
    float a = 0.f;
    for (int i = threadIdx.x; i < n; i += 256) a += partials[i];
    s[threadIdx.x] = a;
    __syncthreads();
    for (int st = 128; st > 0; st >>= 1) {
        if ((int)threadIdx.x < st) s[threadIdx.x] += s[threadIdx.x + st];
        __syncthreads();
    }
    if (threadIdx.x == 0) out[0] = s[0];
}

extern "C" void kernel_launch(void* const* d_in, const int* in_sizes, int n_in,
                              void* d_out, int out_size, void* d_ws, size_t ws_size,
                              hipStream_t stream) {
    const float* z    = (const float*)d_in[0];
    const float* c    = (const float*)d_in[1];
    const float* W    = (const float*)d_in[2];
    const int*   rind = (const int*)d_in[3];

    char* ws = (char*)d_ws;
    u16*   ztr   = (u16*)  (ws + 0);            // 16384*256*2 = 8,388,608 (frag-major)
    float* ctf   = (float*)(ws + 8388608);      // 15360*256*4 = 15,728,640
    u8*    ztwk8 = (u8*)   (ws + 24117248);     // 71680*256   = 18,350,080
    float* parts = (float*)(ws + 42467328);     // 17920*4     = 71,680
    u16*   Wbf   = (u16*)  (ws + 42539008);     // 327680*2    = 655,360 (frag-major)
    float* out   = (float*)d_out;

    transpose_kernel<<<dim3(512, 4, 3), 256, 0, stream>>>(z, c, W, ztr, ctf, Wbf);
    gemm_mfma_kernel<<<dim3(240, 5), 256, 0, stream>>>(ztr, Wbf, ztwk8);
    score_kernel<<<dim3(TOTROWS / 4), 256, 0, stream>>>(ztwk8, ctf, rind, parts);
    reduce_kernel<<<dim3(1), 256, 0, stream>>>(parts, out, TOTROWS / 4);
}